// Round 1
// baseline (511.587 us; speedup 1.0000x reference)
//
#include <hip/hip_runtime.h>
#include <stdint.h>

typedef _Float16 v8h __attribute__((ext_vector_type(8)));
typedef float v4f __attribute__((ext_vector_type(4)));

#define BB 4
#define LL 2048
#define TOPK 32
#define NF 416      // 16 pos + 16 R0 + 24*16 pair RBF
#define NOUT 128

__device__ __constant__ int c_PA[24] = {0,2,3,4,1,1,1,1,0,0,0,4,4,3,0,2,3,4,2,3,4,2,3,2};
__device__ __constant__ int c_PB[24] = {0,2,3,4,0,2,3,4,2,3,4,2,3,2,1,1,1,1,0,0,0,4,4,3};

// ws layout (bytes)
#define OFF_ATOMS 0u            // B*L*5*3 f32 = 491520 B
#define OFF_WT    491520u       // 128*416 f16  = 106496 B
#define OFF_IDX   598016u       // B*L*32 i32   = 1048576 B
#define OFF_DN    1646592u      // B*L*32 f32   = 1048576 B

static __device__ inline _Float16 f2h(float x) { return (_Float16)x; }

// ---------------- prep: atoms (N,Ca,C,O,Cb) + W_edge -> f16 transposed ----------------
__global__ __launch_bounds__(256) void prep_kernel(const float* __restrict__ X,
                                                   const float* __restrict__ W_edge,
                                                   float* __restrict__ atoms,
                                                   _Float16* __restrict__ Wt) {
  int idx = blockIdx.x * 256 + threadIdx.x;
  if (idx < BB * LL) {
    const float* xp = X + (size_t)idx * 12;
    float Nx = xp[0], Ny = xp[1], Nz = xp[2];
    float Cax = xp[3], Cay = xp[4], Caz = xp[5];
    float Cx = xp[6], Cy = xp[7], Cz = xp[8];
    float Ox = xp[9], Oy = xp[10], Oz = xp[11];
    float bx = Cax - Nx, by = Cay - Ny, bz = Caz - Nz;
    float cx = Cx - Cax, cy = Cy - Cay, cz = Cz - Caz;
    float ax = by * cz - bz * cy;
    float ay = bz * cx - bx * cz;
    float az = bx * cy - by * cx;
    float Cbx = -0.58273431f * ax + 0.56802827f * bx - 0.54067466f * cx + Cax;
    float Cby = -0.58273431f * ay + 0.56802827f * by - 0.54067466f * cy + Cay;
    float Cbz = -0.58273431f * az + 0.56802827f * bz - 0.54067466f * cz + Caz;
    float* ap = atoms + (size_t)idx * 15;
    ap[0] = Nx;  ap[1] = Ny;  ap[2] = Nz;
    ap[3] = Cax; ap[4] = Cay; ap[5] = Caz;
    ap[6] = Cx;  ap[7] = Cy;  ap[8] = Cz;
    ap[9] = Ox;  ap[10] = Oy; ap[11] = Oz;
    ap[12] = Cbx; ap[13] = Cby; ap[14] = Cbz;
  } else {
    int t = idx - BB * LL;
    if (t < NOUT * NF) {
      int n = t / NF;
      int k = t - n * NF;
      Wt[t] = f2h(W_edge[(size_t)k * NOUT + n]);  // Wt[n][k] = W_edge[k][n]
    }
  }
}

// ---------------- top-32 nearest Ca neighbors per (b,i), np-bit-matched ----------------
__global__ __launch_bounds__(256) void topk_kernel(const float* __restrict__ X,
                                                   int* __restrict__ idxw,
                                                   float* __restrict__ dnw,
                                                   float* __restrict__ outIdx) {
#pragma clang fp contract(off)
  __shared__ unsigned long long keys[LL];
  __shared__ unsigned long long wmin[2][4];
  int bid = blockIdx.x;
  int b = bid >> 11;
  int i = bid & (LL - 1);
  int tid = threadIdx.x;
  const float* Xb = X + (size_t)b * LL * 12;
  float cix = Xb[i * 12 + 3], ciy = Xb[i * 12 + 4], ciz = Xb[i * 12 + 5];
  unsigned long long lmin = ~0ull;
  for (int t = 0; t < 8; ++t) {
    int j = tid + (t << 8);
    float dx = cix - Xb[j * 12 + 3];
    float dy = ciy - Xb[j * 12 + 4];
    float dz = ciz - Xb[j * 12 + 5];
    float s = ((dx * dx + dy * dy) + dz * dz) + 1e-6f;  // same assoc as np, no fma
    float d = sqrtf(s);                                  // correctly rounded
    unsigned long long key = ((unsigned long long)__float_as_uint(d) << 32) | (unsigned)j;
    keys[j] = key;
    lmin = key < lmin ? key : lmin;
  }
  int lane = tid & 63, wid = tid >> 6;
  for (int k = 0; k < TOPK; ++k) {
    unsigned long long m = lmin;
    for (int off = 32; off; off >>= 1) {
      unsigned long long o = __shfl_down(m, off);
      m = o < m ? o : m;
    }
    if (lane == 0) wmin[k & 1][wid] = m;
    __syncthreads();
    unsigned long long w01 = wmin[k & 1][0] < wmin[k & 1][1] ? wmin[k & 1][0] : wmin[k & 1][1];
    unsigned long long w23 = wmin[k & 1][2] < wmin[k & 1][3] ? wmin[k & 1][2] : wmin[k & 1][3];
    unsigned long long w = w01 < w23 ? w01 : w23;
    int j = (int)(w & 0xffffffffull);
    if (tid == 0) {
      idxw[bid * TOPK + k] = j;
      dnw[bid * TOPK + k] = __uint_as_float((unsigned)(w >> 32));
      outIdx[bid * TOPK + k] = (float)j;  // harness reads flat buffer as f32
    }
    if ((j & 255) == tid) {  // owner invalidates and rescans its 8 keys
      keys[j] = ~0ull;
      unsigned long long nm = ~0ull;
      for (int t = 0; t < 8; ++t) {
        unsigned long long kk = keys[tid + (t << 8)];
        nm = kk < nm ? kk : nm;
      }
      lmin = nm;
    }
  }
}

// ---------------- per-residue: features -> f16 MFMA GEMM -> LayerNorm ----------------
__global__ __launch_bounds__(256) void edge_kernel(
    const float* __restrict__ atoms, const _Float16* __restrict__ Wt,
    const int* __restrict__ idxw, const float* __restrict__ dnw,
    const int* __restrict__ ridx, const int* __restrict__ chain,
    const float* __restrict__ W_pos, const float* __restrict__ b_pos,
    const float* __restrict__ gamma, const float* __restrict__ beta,
    float* __restrict__ outE) {
  __shared__ __align__(16) _Float16 Fb[TOPK][424];  // 416 + pad, 848B row (16B mult)
  __shared__ float dpair[TOPK][24];
  __shared__ float dnbr_s[TOPK];
  __shared__ int dpos_s[TOPK];
  __shared__ int nidx_s[TOPK];
  __shared__ float Et[TOPK][132];
  int bid = blockIdx.x;
  int b = bid >> 11;
  int tid = threadIdx.x;

  if (tid < TOPK) {
    int j = idxw[bid * TOPK + tid];
    nidx_s[tid] = j;
    dnbr_s[tid] = dnw[bid * TOPK + tid];
    int ri = ridx[bid];
    int rj = ridx[b * LL + j];
    int ci = chain[bid];
    int cj = chain[b * LL + j];
    int off = ri - rj + 32;
    off = off < 0 ? 0 : (off > 64 ? 64 : off);
    dpos_s[tid] = (ci == cj) ? off : 65;
  }
  __syncthreads();

  // 24 inter-atom distances per edge
  for (int t = tid; t < TOPK * 24; t += 256) {
    int k = t / 24;
    int p = t - k * 24;
    int j = nidx_s[k];
    const float* aq = atoms + ((size_t)bid * 5 + c_PA[p]) * 3;
    const float* nk = atoms + ((size_t)(b * LL + j) * 5 + c_PB[p]) * 3;
    float dx = aq[0] - nk[0], dy = aq[1] - nk[1], dz = aq[2] - nk[2];
    dpair[k][p] = sqrtf(dx * dx + dy * dy + dz * dz + 1e-6f);
  }
  __syncthreads();

  // fill 32x416 feature matrix (f16)
  const float inv_sigma = 0.8f;  // 1/1.25
  for (int e = tid; e < TOPK * NF; e += 256) {
    int k = e / NF;
    int c = e - k * NF;
    float val;
    if (c < 16) {
      val = W_pos[dpos_s[k] * 16 + c] + b_pos[c];
    } else {
      float d;
      int m;
      if (c < 32) { d = dnbr_s[k]; m = c - 16; }
      else {
        int cc = c - 32;
        d = dpair[k][cc >> 4];
        m = cc & 15;
      }
      float mu = 2.0f + (20.0f / 15.0f) * (float)m;
      float a = (d - mu) * inv_sigma;
      val = __expf(-a * a);
    }
    Fb[k][c] = f2h(val);
  }
  __syncthreads();

  // GEMM 32x416 @ 416x128 via mfma_f32_16x16x32_f16
  int lane = tid & 63, wid = tid >> 6;
  int mt = wid & 1;      // M-tile (16 edges)
  int nh = wid >> 1;     // N-half (64 outputs)
  int lm = lane & 15, lq = lane >> 4;
  v4f acc0 = {0.f, 0.f, 0.f, 0.f}, acc1 = acc0, acc2 = acc0, acc3 = acc0;
  const _Float16* w0 = Wt + ((size_t)(nh * 64 + 0 + lm)) * NF + lq * 8;
  const _Float16* w1 = w0 + 16 * NF;
  const _Float16* w2 = w0 + 32 * NF;
  const _Float16* w3 = w0 + 48 * NF;
  const _Float16* ap = &Fb[mt * 16 + lm][lq * 8];
  for (int kk = 0; kk < 13; ++kk) {
    int k0 = kk * 32;
    v8h a = *(const v8h*)(ap + k0);
    v8h b0 = *(const v8h*)(w0 + k0);
    v8h b1 = *(const v8h*)(w1 + k0);
    v8h b2 = *(const v8h*)(w2 + k0);
    v8h b3 = *(const v8h*)(w3 + k0);
    acc0 = __builtin_amdgcn_mfma_f32_16x16x32_f16(a, b0, acc0, 0, 0, 0);
    acc1 = __builtin_amdgcn_mfma_f32_16x16x32_f16(a, b1, acc1, 0, 0, 0);
    acc2 = __builtin_amdgcn_mfma_f32_16x16x32_f16(a, b2, acc2, 0, 0, 0);
    acc3 = __builtin_amdgcn_mfma_f32_16x16x32_f16(a, b3, acc3, 0, 0, 0);
  }
  {
    int r0 = mt * 16 + lq * 4;       // C/D: row = quad*4 + reg  (m89-verified)
    int cb = nh * 64 + lm;           //      col = lane&15
    for (int r = 0; r < 4; ++r) {
      Et[r0 + r][cb + 0]  = acc0[r];
      Et[r0 + r][cb + 16] = acc1[r];
      Et[r0 + r][cb + 32] = acc2[r];
      Et[r0 + r][cb + 48] = acc3[r];
    }
  }
  __syncthreads();

  // LayerNorm over 128 per edge; 8 lanes per edge (contiguous in wave)
  {
    int k = tid >> 3, g = tid & 7;
    const float* row = &Et[k][0];
    float v[16];
    float s = 0.f, ss = 0.f;
    for (int q = 0; q < 16; ++q) {
      float x = row[g * 16 + q];
      v[q] = x;
      s += x;
      ss += x * x;
    }
    s += __shfl_xor(s, 1); ss += __shfl_xor(ss, 1);
    s += __shfl_xor(s, 2); ss += __shfl_xor(ss, 2);
    s += __shfl_xor(s, 4); ss += __shfl_xor(ss, 4);
    float mean = s * (1.0f / 128.0f);
    float var = ss * (1.0f / 128.0f) - mean * mean;
    float rstd = 1.0f / sqrtf(var + 1e-5f);
    float* op = outE + ((size_t)bid * TOPK + k) * NOUT + g * 16;
    for (int q = 0; q < 16; ++q) {
      int n = g * 16 + q;
      op[q] = (v[q] - mean) * rstd * gamma[n] + beta[n];
    }
  }
}

extern "C" void kernel_launch(void* const* d_in, const int* in_sizes, int n_in,
                              void* d_out, int out_size, void* d_ws, size_t ws_size,
                              hipStream_t stream) {
  const float* X = (const float*)d_in[0];
  const int* ridx = (const int*)d_in[2];
  const int* chain = (const int*)d_in[3];
  const float* W_pos = (const float*)d_in[4];
  const float* b_pos = (const float*)d_in[5];
  const float* W_edge = (const float*)d_in[6];
  const float* gamma = (const float*)d_in[7];
  const float* beta = (const float*)d_in[8];

  float* outE = (float*)d_out;
  float* outIdx = outE + (size_t)BB * LL * TOPK * NOUT;

  char* ws = (char*)d_ws;
  float* atoms = (float*)(ws + OFF_ATOMS);
  _Float16* Wt = (_Float16*)(ws + OFF_WT);
  int* idxw = (int*)(ws + OFF_IDX);
  float* dnw = (float*)(ws + OFF_DN);

  prep_kernel<<<240, 256, 0, stream>>>(X, W_edge, atoms, Wt);
  topk_kernel<<<BB * LL, 256, 0, stream>>>(X, idxw, dnw, outIdx);
  edge_kernel<<<BB * LL, 256, 0, stream>>>(atoms, Wt, idxw, dnw, ridx, chain,
                                           W_pos, b_pos, gamma, beta, outE);
}

// Round 2
// 439.714 us; speedup vs baseline: 1.1635x; 1.1635x over previous
//
#include <hip/hip_runtime.h>
#include <stdint.h>

typedef _Float16 v8h __attribute__((ext_vector_type(8)));
typedef _Float16 v2h __attribute__((ext_vector_type(2)));
typedef float v4f __attribute__((ext_vector_type(4)));

#define BB 4
#define LL 2048
#define TOPK 32
#define NF 416      // 16 pos + 16 R0 + 24*16 pair RBF
#define NOUT 128
#define FBS 424     // Fb row stride (f16): 848B, 16B-aligned, stride%32words=20 -> 2-way max

__device__ __constant__ int c_PA[24] = {0,2,3,4,1,1,1,1,0,0,0,4,4,3,0,2,3,4,2,3,4,2,3,2};
__device__ __constant__ int c_PB[24] = {0,2,3,4,0,2,3,4,2,3,4,2,3,2,1,1,1,1,0,0,0,4,4,3};

// ws layout (bytes)
#define OFF_ATOMS 0u            // B*L*5*3 f32 = 491520 B
#define OFF_WT    491520u       // 128*416 f16  = 106496 B
#define OFF_IDX   598016u       // B*L*32 i32   = 1048576 B
#define OFF_DN    1646592u      // B*L*32 f32   = 1048576 B

static __device__ inline _Float16 f2h(float x) { return (_Float16)x; }

// ---------------- prep: atoms (N,Ca,C,O,Cb) + W_edge -> f16 transposed ----------------
__global__ __launch_bounds__(256) void prep_kernel(const float* __restrict__ X,
                                                   const float* __restrict__ W_edge,
                                                   float* __restrict__ atoms,
                                                   _Float16* __restrict__ Wt) {
  int idx = blockIdx.x * 256 + threadIdx.x;
  if (idx < BB * LL) {
    const float* xp = X + (size_t)idx * 12;
    float Nx = xp[0], Ny = xp[1], Nz = xp[2];
    float Cax = xp[3], Cay = xp[4], Caz = xp[5];
    float Cx = xp[6], Cy = xp[7], Cz = xp[8];
    float Ox = xp[9], Oy = xp[10], Oz = xp[11];
    float bx = Cax - Nx, by = Cay - Ny, bz = Caz - Nz;
    float cx = Cx - Cax, cy = Cy - Cay, cz = Cz - Caz;
    float ax = by * cz - bz * cy;
    float ay = bz * cx - bx * cz;
    float az = bx * cy - by * cx;
    float Cbx = -0.58273431f * ax + 0.56802827f * bx - 0.54067466f * cx + Cax;
    float Cby = -0.58273431f * ay + 0.56802827f * by - 0.54067466f * cy + Cay;
    float Cbz = -0.58273431f * az + 0.56802827f * bz - 0.54067466f * cz + Caz;
    float* ap = atoms + (size_t)idx * 15;
    ap[0] = Nx;  ap[1] = Ny;  ap[2] = Nz;
    ap[3] = Cax; ap[4] = Cay; ap[5] = Caz;
    ap[6] = Cx;  ap[7] = Cy;  ap[8] = Cz;
    ap[9] = Ox;  ap[10] = Oy; ap[11] = Oz;
    ap[12] = Cbx; ap[13] = Cby; ap[14] = Cbz;
  } else {
    int t = idx - BB * LL;
    if (t < NOUT * NF) {
      int n = t / NF;
      int k = t - n * NF;
      Wt[t] = f2h(W_edge[(size_t)k * NOUT + n]);  // Wt[n][k] = W_edge[k][n]
    }
  }
}

// ---------------- top-32: wave-local register top-32 + single-wave merge ----------------
// Keys identical to previous (passing) version: ((bits(d)<<32)|j), same fp op order.
__global__ __launch_bounds__(256, 6) void topk_kernel(const float* __restrict__ X,
                                                      int* __restrict__ idxw,
                                                      float* __restrict__ dnw,
                                                      float* __restrict__ outIdx) {
#pragma clang fp contract(off)
  __shared__ unsigned long long smem[128];
  int bid = blockIdx.x;
  int b = bid >> 11;
  int i = bid & (LL - 1);
  int tid = threadIdx.x;
  int lane = tid & 63, wid = tid >> 6;
  const float* Xb = X + (size_t)b * LL * 12;
  float cix = Xb[i * 12 + 3], ciy = Xb[i * 12 + 4], ciz = Xb[i * 12 + 5];
  unsigned long long key[8];
  unsigned long long lmin = ~0ull;
#pragma unroll
  for (int t = 0; t < 8; ++t) {
    int j = (wid << 9) + (t << 6) + lane;
    float dx = cix - Xb[j * 12 + 3];
    float dy = ciy - Xb[j * 12 + 4];
    float dz = ciz - Xb[j * 12 + 5];
    float s = ((dx * dx + dy * dy) + dz * dz) + 1e-6f;  // np association, no fma
    float d = sqrtf(s);
    key[t] = ((unsigned long long)__float_as_uint(d) << 32) | (unsigned)j;
    lmin = key[t] < lmin ? key[t] : lmin;
  }
  // 32 shuffle-only argmin rounds per wave (keys unique -> unique owner)
  unsigned long long sel = 0;
  for (int k = 0; k < TOPK; ++k) {
    unsigned long long m = lmin;
#pragma unroll
    for (int off = 32; off; off >>= 1) {
      unsigned long long o = __shfl_xor(m, off);
      m = o < m ? o : m;
    }
    if (lane == k) sel = m;
    if (lmin == m) {  // owner: drop the winner, recompute local min
      unsigned long long nm = ~0ull;
#pragma unroll
      for (int t = 0; t < 8; ++t) {
        key[t] = (key[t] == m) ? ~0ull : key[t];
        nm = key[t] < nm ? key[t] : nm;
      }
      lmin = nm;
    }
  }
  if (lane < TOPK) smem[wid * TOPK + lane] = sel;
  __syncthreads();
  if (wid == 0) {  // merge 4 sorted 32-lists (128 keys, 2/lane)
    unsigned long long k0 = smem[lane], k1 = smem[64 + lane];
    unsigned long long lm2 = k0 < k1 ? k0 : k1;
    for (int k = 0; k < TOPK; ++k) {
      unsigned long long m = lm2;
#pragma unroll
      for (int off = 32; off; off >>= 1) {
        unsigned long long o = __shfl_xor(m, off);
        m = o < m ? o : m;
      }
      if (lane == k) sel = m;
      if (lm2 == m) {
        k0 = (k0 == m) ? ~0ull : k0;
        k1 = (k1 == m) ? ~0ull : k1;
        lm2 = k0 < k1 ? k0 : k1;
      }
    }
    if (lane < TOPK) {
      int j = (int)(sel & 0xffffffffull);
      idxw[bid * TOPK + lane] = j;
      dnw[bid * TOPK + lane] = __uint_as_float((unsigned)(sel >> 32));
      outIdx[bid * TOPK + lane] = (float)j;  // harness reads flat f32
    }
  }
}

// ---------------- per-residue: features -> f16 MFMA GEMM -> fused LayerNorm ----------------
__global__ __launch_bounds__(256, 4) void edge_kernel(
    const float* __restrict__ atoms, const _Float16* __restrict__ Wt,
    const int* __restrict__ idxw, const float* __restrict__ dnw,
    const int* __restrict__ ridx, const int* __restrict__ chain,
    const float* __restrict__ W_pos, const float* __restrict__ b_pos,
    const float* __restrict__ gamma, const float* __restrict__ beta,
    float* __restrict__ outE) {
  __shared__ __align__(16) _Float16 Fb[TOPK][FBS];  // 27136 B
  __shared__ float partS[TOPK][2];
  __shared__ float partQ[TOPK][2];
  __shared__ float dnbr_s[TOPK];
  __shared__ int dpos_s[TOPK];
  __shared__ int nidx_s[TOPK];
  __shared__ float qa[15];
  int bid = blockIdx.x;
  int b = bid >> 11;
  int tid = threadIdx.x;

  if (tid < TOPK) {
    int j = idxw[bid * TOPK + tid];
    nidx_s[tid] = j;
    dnbr_s[tid] = dnw[bid * TOPK + tid];
    int ri = ridx[bid], rj = ridx[b * LL + j];
    int off = ri - rj + 32;
    off = off < 0 ? 0 : (off > 64 ? 64 : off);
    dpos_s[tid] = (chain[bid] == chain[b * LL + j]) ? off : 65;
  } else if (tid >= 64 && tid < 79) {
    qa[tid - 64] = atoms[(size_t)bid * 15 + (tid - 64)];
  }
  __syncthreads();

  // fill 32x416 f16 feature tile; 8 threads per edge, no div/mod, 16B LDS stores
  {
    int k = tid >> 3, g = tid & 7;
    {
      int dp = dpos_s[k];
      int c = g * 2;
      float v0 = W_pos[dp * 16 + c] + b_pos[c];
      float v1 = W_pos[dp * 16 + c + 1] + b_pos[c + 1];
      v2h hv;
      hv[0] = (_Float16)v0;
      hv[1] = (_Float16)v1;
      *(v2h*)&Fb[k][c] = hv;
    }
    const float* nb = atoms + (size_t)(b * LL + nidx_s[k]) * 15;
    for (int p = g; p < 25; p += 8) {
      float d;
      if (p == 0) {
        d = dnbr_s[k];
      } else {
        int pp = p - 1;
        int ia = c_PA[pp] * 3, ib = c_PB[pp] * 3;
        float dx = qa[ia] - nb[ib];
        float dy = qa[ia + 1] - nb[ib + 1];
        float dz = qa[ia + 2] - nb[ib + 2];
        d = sqrtf(dx * dx + dy * dy + dz * dz + 1e-6f);
      }
      v8h h0, h1;
#pragma unroll
      for (int m = 0; m < 16; ++m) {
        float mu = 2.0f + (20.0f / 15.0f) * (float)m;  // compile-time folded
        float a = (d - mu) * 0.8f;
        float val = __expf(-a * a);
        if (m < 8) h0[m] = (_Float16)val;
        else h1[m - 8] = (_Float16)val;
      }
      *(v8h*)&Fb[k][16 + p * 16] = h0;
      *(v8h*)&Fb[k][24 + p * 16] = h1;
    }
  }
  __syncthreads();

  // GEMM 32x416 @ 416x128: wave -> (mt: 16 rows, nh: 64 cols), 4 16-col tiles
  int lane = tid & 63, wid = tid >> 6;
  int mt = wid & 1, nh = wid >> 1;
  int lm = lane & 15, lq = lane >> 4;
  float gm[4], bt[4];
#pragma unroll
  for (int t = 0; t < 4; ++t) {
    gm[t] = gamma[nh * 64 + t * 16 + lm];
    bt[t] = beta[nh * 64 + t * 16 + lm];
  }
  v4f acc0 = {0.f, 0.f, 0.f, 0.f}, acc1 = acc0, acc2 = acc0, acc3 = acc0;
  const _Float16* w0 = Wt + (size_t)(nh * 64 + lm) * NF + lq * 8;
  const _Float16* ap = &Fb[mt * 16 + lm][lq * 8];
#pragma unroll
  for (int kk = 0; kk < 13; ++kk) {
    int k0 = kk * 32;
    v8h a = *(const v8h*)(ap + k0);
    v8h b0 = *(const v8h*)(w0 + k0);
    v8h b1 = *(const v8h*)(w0 + 16 * NF + k0);
    v8h b2 = *(const v8h*)(w0 + 32 * NF + k0);
    v8h b3 = *(const v8h*)(w0 + 48 * NF + k0);
    acc0 = __builtin_amdgcn_mfma_f32_16x16x32_f16(a, b0, acc0, 0, 0, 0);
    acc1 = __builtin_amdgcn_mfma_f32_16x16x32_f16(a, b1, acc1, 0, 0, 0);
    acc2 = __builtin_amdgcn_mfma_f32_16x16x32_f16(a, b2, acc2, 0, 0, 0);
    acc3 = __builtin_amdgcn_mfma_f32_16x16x32_f16(a, b3, acc3, 0, 0, 0);
  }

  // LayerNorm from registers: per-row half-sums via 512B LDS
#pragma unroll
  for (int r = 0; r < 4; ++r) {
    float s = acc0[r] + acc1[r] + acc2[r] + acc3[r];
    float q = acc0[r] * acc0[r] + acc1[r] * acc1[r] + acc2[r] * acc2[r] + acc3[r] * acc3[r];
#pragma unroll
    for (int off = 1; off <= 8; off <<= 1) {
      s += __shfl_xor(s, off);
      q += __shfl_xor(q, off);
    }
    if (lm == 0) {
      int row = mt * 16 + lq * 4 + r;
      partS[row][nh] = s;
      partQ[row][nh] = q;
    }
  }
  __syncthreads();
  float* op = outE + (size_t)bid * TOPK * NOUT;
#pragma unroll
  for (int r = 0; r < 4; ++r) {
    int row = mt * 16 + lq * 4 + r;
    float S = partS[row][0] + partS[row][1];
    float Q = partQ[row][0] + partQ[row][1];
    float mean = S * (1.0f / 128.0f);
    float var = Q * (1.0f / 128.0f) - mean * mean;
    float rstd = 1.0f / sqrtf(var + 1e-5f);
    float vr0 = acc0[r], vr1 = acc1[r], vr2 = acc2[r], vr3 = acc3[r];
    float* row_p = op + (size_t)row * NOUT + nh * 64 + lm;
    row_p[0]  = (vr0 - mean) * rstd * gm[0] + bt[0];
    row_p[16] = (vr1 - mean) * rstd * gm[1] + bt[1];
    row_p[32] = (vr2 - mean) * rstd * gm[2] + bt[2];
    row_p[48] = (vr3 - mean) * rstd * gm[3] + bt[3];
  }
}

extern "C" void kernel_launch(void* const* d_in, const int* in_sizes, int n_in,
                              void* d_out, int out_size, void* d_ws, size_t ws_size,
                              hipStream_t stream) {
  const float* X = (const float*)d_in[0];
  const int* ridx = (const int*)d_in[2];
  const int* chain = (const int*)d_in[3];
  const float* W_pos = (const float*)d_in[4];
  const float* b_pos = (const float*)d_in[5];
  const float* W_edge = (const float*)d_in[6];
  const float* gamma = (const float*)d_in[7];
  const float* beta = (const float*)d_in[8];

  float* outE = (float*)d_out;
  float* outIdx = outE + (size_t)BB * LL * TOPK * NOUT;

  char* ws = (char*)d_ws;
  float* atoms = (float*)(ws + OFF_ATOMS);
  _Float16* Wt = (_Float16*)(ws + OFF_WT);
  int* idxw = (int*)(ws + OFF_IDX);
  float* dnw = (float*)(ws + OFF_DN);

  prep_kernel<<<240, 256, 0, stream>>>(X, W_edge, atoms, Wt);
  topk_kernel<<<BB * LL, 256, 0, stream>>>(X, idxw, dnw, outIdx);
  edge_kernel<<<BB * LL, 256, 0, stream>>>(atoms, Wt, idxw, dnw, ridx, chain,
                                           W_pos, b_pos, gamma, beta, outE);
}

// Round 3
// 292.274 us; speedup vs baseline: 1.7504x; 1.5045x over previous
//
#include <hip/hip_runtime.h>
#include <stdint.h>

typedef _Float16 v8h __attribute__((ext_vector_type(8)));
typedef _Float16 v2h __attribute__((ext_vector_type(2)));
typedef float v4f __attribute__((ext_vector_type(4)));

#define BB 4
#define LL 2048
#define TOPK 32
#define NF 416      // 16 pos + 16 R0 + 24*16 pair RBF
#define NOUT 128
#define FBS 424     // Fb row stride (f16)
#define NBINS 4096
#define NCAND 128

__device__ __constant__ int c_PA[24] = {0,2,3,4,1,1,1,1,0,0,0,4,4,3,0,2,3,4,2,3,4,2,3,2};
__device__ __constant__ int c_PB[24] = {0,2,3,4,0,2,3,4,2,3,4,2,3,2,1,1,1,1,0,0,0,4,4,3};

// ws layout (bytes)
#define OFF_ATOMS 0u            // B*L*5*3 f32 = 491520 B
#define OFF_WT    491520u       // 128*416 f16  = 106496 B
#define OFF_IDX   598016u       // B*L*32 i32   = 1048576 B
#define OFF_DN    1646592u      // B*L*32 f32   = 1048576 B

static __device__ inline _Float16 f2h(float x) { return (_Float16)x; }
static __device__ inline unsigned long long umin64(unsigned long long a, unsigned long long b) {
  return a < b ? a : b;
}
static __device__ inline unsigned long long umax64(unsigned long long a, unsigned long long b) {
  return a > b ? a : b;
}

// ---------------- prep: atoms (N,Ca,C,O,Cb) + W_edge -> f16 transposed ----------------
__global__ __launch_bounds__(256) void prep_kernel(const float* __restrict__ X,
                                                   const float* __restrict__ W_edge,
                                                   float* __restrict__ atoms,
                                                   _Float16* __restrict__ Wt) {
  int idx = blockIdx.x * 256 + threadIdx.x;
  if (idx < BB * LL) {
    const float* xp = X + (size_t)idx * 12;
    float Nx = xp[0], Ny = xp[1], Nz = xp[2];
    float Cax = xp[3], Cay = xp[4], Caz = xp[5];
    float Cx = xp[6], Cy = xp[7], Cz = xp[8];
    float Ox = xp[9], Oy = xp[10], Oz = xp[11];
    float bx = Cax - Nx, by = Cay - Ny, bz = Caz - Nz;
    float cx = Cx - Cax, cy = Cy - Cay, cz = Cz - Caz;
    float ax = by * cz - bz * cy;
    float ay = bz * cx - bx * cz;
    float az = bx * cy - by * cx;
    float Cbx = -0.58273431f * ax + 0.56802827f * bx - 0.54067466f * cx + Cax;
    float Cby = -0.58273431f * ay + 0.56802827f * by - 0.54067466f * cy + Cay;
    float Cbz = -0.58273431f * az + 0.56802827f * bz - 0.54067466f * cz + Caz;
    float* ap = atoms + (size_t)idx * 15;
    ap[0] = Nx;  ap[1] = Ny;  ap[2] = Nz;
    ap[3] = Cax; ap[4] = Cay; ap[5] = Caz;
    ap[6] = Cx;  ap[7] = Cy;  ap[8] = Cz;
    ap[9] = Ox;  ap[10] = Oy; ap[11] = Oz;
    ap[12] = Cbx; ap[13] = Cby; ap[14] = Cbz;
  } else {
    int t = idx - BB * LL;
    if (t < NOUT * NF) {
      int n = t / NF;
      int k = t - n * NF;
      Wt[t] = f2h(W_edge[(size_t)k * NOUT + n]);  // Wt[n][k] = W_edge[k][n]
    }
  }
}

// ---------------- top-32 via histogram radix-select + exact bitonic sort ----------------
// Key = ((bits(d)<<32)|j): monotone for d>0, tie -> lower index; same fp op order as before.
__global__ __launch_bounds__(256) void topk_kernel(const float* __restrict__ X,
                                                   int* __restrict__ idxw,
                                                   float* __restrict__ dnw,
                                                   float* __restrict__ outIdx) {
#pragma clang fp contract(off)
  __shared__ int hist[NBINS];
  __shared__ unsigned long long cand[NCAND];
  __shared__ int cnt;
  __shared__ int cb_s;
  __shared__ int wtot[4];
  int bid = blockIdx.x;
  int b = bid >> 11;
  int i = bid & (LL - 1);
  int tid = threadIdx.x;
  int lane = tid & 63, wid = tid >> 6;

  // Phase A: zero hist + cand
  for (int t = tid; t < NBINS; t += 256) hist[t] = 0;
  if (tid < NCAND) cand[tid] = ~0ull;
  if (tid == 0) cnt = 0;

  const float* Xb = X + (size_t)b * LL * 12;
  float cix = Xb[i * 12 + 3], ciy = Xb[i * 12 + 4], ciz = Xb[i * 12 + 5];
  unsigned long long key[8];
#pragma unroll
  for (int t = 0; t < 8; ++t) {
    int j = tid + (t << 8);
    float dx = cix - Xb[j * 12 + 3];
    float dy = ciy - Xb[j * 12 + 4];
    float dz = ciz - Xb[j * 12 + 5];
    float s = ((dx * dx + dy * dy) + dz * dz) + 1e-6f;  // np association, no fma
    float d = sqrtf(s);
    key[t] = ((unsigned long long)__float_as_uint(d) << 32) | (unsigned)j;
  }
  __syncthreads();  // hist zeroed
  // Phase B: histogram of top (sign+exp+4 mantissa) bits
#pragma unroll
  for (int t = 0; t < 8; ++t) {
    atomicAdd(&hist[(int)(key[t] >> 51)], 1);
  }
  __syncthreads();

  // Phase C: block scan over 256 thread-partials (16 bins each); find crossing bin
  int base_bin = tid * (NBINS / 256);
  int psum = 0;
#pragma unroll
  for (int t = 0; t < NBINS / 256; ++t) psum += hist[base_bin + t];
  int incl = psum;
#pragma unroll
  for (int off = 1; off < 64; off <<= 1) {
    int o = __shfl_up(incl, off);
    if (lane >= off) incl += o;
  }
  if (lane == 63) wtot[wid] = incl;
  __syncthreads();
  int wbase = 0;
  for (int w = 0; w < wid; ++w) wbase += wtot[w];
  int base = wbase + incl - psum;  // exclusive prefix for this thread's 16 bins
  if (base < TOPK && base + psum >= TOPK) {
    int run = base;
    for (int t = 0; t < NBINS / 256; ++t) {
      int h = hist[base_bin + t];
      if (run < TOPK && run + h >= TOPK) { cb_s = base_bin + t; break; }
      run += h;
    }
  }
  __syncthreads();

  // Phase D: collect all keys with bucket <= crossing bin (guaranteed >= 32 of them)
  int cb = cb_s;
#pragma unroll
  for (int t = 0; t < 8; ++t) {
    if ((int)(key[t] >> 51) <= cb) {
      int slot = atomicAdd(&cnt, 1);
      if (slot < NCAND) cand[slot] = key[t];
    }
  }
  __syncthreads();

  // Phase E: wave 0 bitonic-sorts 128 candidates (2 elements/lane), writes top-32
  if (wid == 0) {
    unsigned long long x = cand[lane];        // element index = lane
    unsigned long long y = cand[lane + 64];   // element index = lane + 64
#pragma unroll
    for (int k = 2; k <= 128; k <<= 1) {
#pragma unroll
      for (int j = 64; j >= 1; j >>= 1) {
        if (j >= k) continue;
        if (j == 64) {
          // partner across x/y within lane; k==128 -> ascending for all
          unsigned long long mn = umin64(x, y), mx = umax64(x, y);
          x = mn; y = mx;
        } else {
          unsigned long long px = __shfl_xor(x, j);
          bool upx = ((lane & k) == 0);
          bool lowx = ((lane & j) == 0);
          x = (lowx == upx) ? umin64(x, px) : umax64(x, px);
          unsigned long long py = __shfl_xor(y, j);
          bool upy = (((lane + 64) & k) == 0);
          y = (lowx == upy) ? umin64(y, py) : umax64(y, py);
        }
      }
    }
    if (lane < TOPK) {
      unsigned long long sel = x;  // ascending: lanes 0..31 hold 32 smallest
      int j = (int)(sel & 0xffffffffull);
      idxw[bid * TOPK + lane] = j;
      dnw[bid * TOPK + lane] = __uint_as_float((unsigned)(sel >> 32));
      outIdx[bid * TOPK + lane] = (float)j;  // harness reads flat f32
    }
  }
}

// ---------------- per-residue: features -> f16 MFMA GEMM -> fused LayerNorm ----------------
__global__ __launch_bounds__(256, 5) void edge_kernel(
    const float* __restrict__ atoms, const _Float16* __restrict__ Wt,
    const int* __restrict__ idxw, const float* __restrict__ dnw,
    const int* __restrict__ ridx, const int* __restrict__ chain,
    const float* __restrict__ W_pos, const float* __restrict__ b_pos,
    const float* __restrict__ gamma, const float* __restrict__ beta,
    float* __restrict__ outE) {
  __shared__ __align__(16) _Float16 Fb[TOPK][FBS];  // 27136 B
  __shared__ float partS[TOPK][2];
  __shared__ float partQ[TOPK][2];
  __shared__ float dnbr_s[TOPK];
  __shared__ int dpos_s[TOPK];
  __shared__ int nidx_s[TOPK];
  __shared__ float qa[15];
  int bid = blockIdx.x;
  int b = bid >> 11;
  int tid = threadIdx.x;

  if (tid < TOPK) {
    int j = idxw[bid * TOPK + tid];
    nidx_s[tid] = j;
    dnbr_s[tid] = dnw[bid * TOPK + tid];
    int ri = ridx[bid], rj = ridx[b * LL + j];
    int off = ri - rj + 32;
    off = off < 0 ? 0 : (off > 64 ? 64 : off);
    dpos_s[tid] = (chain[bid] == chain[b * LL + j]) ? off : 65;
  } else if (tid >= 64 && tid < 79) {
    qa[tid - 64] = atoms[(size_t)bid * 15 + (tid - 64)];
  }
  __syncthreads();

  // fill 32x416 f16 feature tile; 8 threads per edge, no div/mod, 16B LDS stores
  {
    int k = tid >> 3, g = tid & 7;
    {
      int dp = dpos_s[k];
      int c = g * 2;
      float v0 = W_pos[dp * 16 + c] + b_pos[c];
      float v1 = W_pos[dp * 16 + c + 1] + b_pos[c + 1];
      v2h hv;
      hv[0] = (_Float16)v0;
      hv[1] = (_Float16)v1;
      *(v2h*)&Fb[k][c] = hv;
    }
    const float* nb = atoms + (size_t)(b * LL + nidx_s[k]) * 15;
    for (int p = g; p < 25; p += 8) {
      float d;
      if (p == 0) {
        d = dnbr_s[k];
      } else {
        int pp = p - 1;
        int ia = c_PA[pp] * 3, ib = c_PB[pp] * 3;
        float dx = qa[ia] - nb[ib];
        float dy = qa[ia + 1] - nb[ib + 1];
        float dz = qa[ia + 2] - nb[ib + 2];
        d = sqrtf(dx * dx + dy * dy + dz * dz + 1e-6f);
      }
      v8h h0, h1;
#pragma unroll
      for (int m = 0; m < 16; ++m) {
        float mu = 2.0f + (20.0f / 15.0f) * (float)m;  // compile-time folded
        float a = (d - mu) * 0.8f;
        float val = __expf(-a * a);
        if (m < 8) h0[m] = (_Float16)val;
        else h1[m - 8] = (_Float16)val;
      }
      *(v8h*)&Fb[k][16 + p * 16] = h0;
      *(v8h*)&Fb[k][24 + p * 16] = h1;
    }
  }
  __syncthreads();

  // GEMM 32x416 @ 416x128: wave -> (mt: 16 rows, nh: 64 cols), 4 16-col tiles
  int lane = tid & 63, wid = tid >> 6;
  int mt = wid & 1, nh = wid >> 1;
  int lm = lane & 15, lq = lane >> 4;
  float gm[4], bt[4];
#pragma unroll
  for (int t = 0; t < 4; ++t) {
    gm[t] = gamma[nh * 64 + t * 16 + lm];
    bt[t] = beta[nh * 64 + t * 16 + lm];
  }
  v4f acc0 = {0.f, 0.f, 0.f, 0.f}, acc1 = acc0, acc2 = acc0, acc3 = acc0;
  const _Float16* w0 = Wt + (size_t)(nh * 64 + lm) * NF + lq * 8;
  const _Float16* ap = &Fb[mt * 16 + lm][lq * 8];
#pragma unroll
  for (int kk = 0; kk < 13; ++kk) {
    int k0 = kk * 32;
    v8h a = *(const v8h*)(ap + k0);
    v8h b0 = *(const v8h*)(w0 + k0);
    v8h b1 = *(const v8h*)(w0 + 16 * NF + k0);
    v8h b2 = *(const v8h*)(w0 + 32 * NF + k0);
    v8h b3 = *(const v8h*)(w0 + 48 * NF + k0);
    acc0 = __builtin_amdgcn_mfma_f32_16x16x32_f16(a, b0, acc0, 0, 0, 0);
    acc1 = __builtin_amdgcn_mfma_f32_16x16x32_f16(a, b1, acc1, 0, 0, 0);
    acc2 = __builtin_amdgcn_mfma_f32_16x16x32_f16(a, b2, acc2, 0, 0, 0);
    acc3 = __builtin_amdgcn_mfma_f32_16x16x32_f16(a, b3, acc3, 0, 0, 0);
  }

  // LayerNorm from registers: per-row half-sums via 512B LDS
#pragma unroll
  for (int r = 0; r < 4; ++r) {
    float s = acc0[r] + acc1[r] + acc2[r] + acc3[r];
    float q = acc0[r] * acc0[r] + acc1[r] * acc1[r] + acc2[r] * acc2[r] + acc3[r] * acc3[r];
#pragma unroll
    for (int off = 1; off <= 8; off <<= 1) {
      s += __shfl_xor(s, off);
      q += __shfl_xor(q, off);
    }
    if (lm == 0) {
      int row = mt * 16 + lq * 4 + r;
      partS[row][nh] = s;
      partQ[row][nh] = q;
    }
  }
  __syncthreads();
  float* op = outE + (size_t)bid * TOPK * NOUT;
#pragma unroll
  for (int r = 0; r < 4; ++r) {
    int row = mt * 16 + lq * 4 + r;
    float S = partS[row][0] + partS[row][1];
    float Q = partQ[row][0] + partQ[row][1];
    float mean = S * (1.0f / 128.0f);
    float var = Q * (1.0f / 128.0f) - mean * mean;
    float rstd = 1.0f / sqrtf(var + 1e-5f);
    float vr0 = acc0[r], vr1 = acc1[r], vr2 = acc2[r], vr3 = acc3[r];
    float* row_p = op + (size_t)row * NOUT + nh * 64 + lm;
    row_p[0]  = (vr0 - mean) * rstd * gm[0] + bt[0];
    row_p[16] = (vr1 - mean) * rstd * gm[1] + bt[1];
    row_p[32] = (vr2 - mean) * rstd * gm[2] + bt[2];
    row_p[48] = (vr3 - mean) * rstd * gm[3] + bt[3];
  }
}

extern "C" void kernel_launch(void* const* d_in, const int* in_sizes, int n_in,
                              void* d_out, int out_size, void* d_ws, size_t ws_size,
                              hipStream_t stream) {
  const float* X = (const float*)d_in[0];
  const int* ridx = (const int*)d_in[2];
  const int* chain = (const int*)d_in[3];
  const float* W_pos = (const float*)d_in[4];
  const float* b_pos = (const float*)d_in[5];
  const float* W_edge = (const float*)d_in[6];
  const float* gamma = (const float*)d_in[7];
  const float* beta = (const float*)d_in[8];

  float* outE = (float*)d_out;
  float* outIdx = outE + (size_t)BB * LL * TOPK * NOUT;

  char* ws = (char*)d_ws;
  float* atoms = (float*)(ws + OFF_ATOMS);
  _Float16* Wt = (_Float16*)(ws + OFF_WT);
  int* idxw = (int*)(ws + OFF_IDX);
  float* dnw = (float*)(ws + OFF_DN);

  prep_kernel<<<240, 256, 0, stream>>>(X, W_edge, atoms, Wt);
  topk_kernel<<<BB * LL, 256, 0, stream>>>(X, idxw, dnw, outIdx);
  edge_kernel<<<BB * LL, 256, 0, stream>>>(atoms, Wt, idxw, dnw, ridx, chain,
                                           W_pos, b_pos, gamma, beta, outE);
}

// Round 4
// 243.278 us; speedup vs baseline: 2.1029x; 1.2014x over previous
//
#include <hip/hip_runtime.h>
#include <stdint.h>

typedef _Float16 v8h __attribute__((ext_vector_type(8)));
typedef _Float16 v4h __attribute__((ext_vector_type(4)));
typedef float v4f __attribute__((ext_vector_type(4)));

#define BB 4
#define LL 2048
#define TOPK 32
#define NF 416      // 16 pos + 16 R0 + 24*16 pair RBF
#define NOUT 128
#define NBINS 4096
#define NCAND 128
#define FBS 232     // Fb row stride in halves (464 B, 16B-aligned)

__device__ __constant__ int c_PA[24] = {0,2,3,4,1,1,1,1,0,0,0,4,4,3,0,2,3,4,2,3,4,2,3,2};
__device__ __constant__ int c_PB[24] = {0,2,3,4,0,2,3,4,2,3,4,2,3,2,1,1,1,1,0,0,0,4,4,3};

// ws layout (bytes)
#define OFF_ATOMS 0u            // B*L*16 f32 (4x float4/residue) = 524288 B
#define OFF_CA    524288u       // B*L float4                     = 131072 B
#define OFF_WT    655360u       // 128*416 f16                    = 106496 B

// np-bit-matched distance: ((dx*dx+dy*dy)+dz*dz)+1e-6, no fma, exact sqrt
static __device__ inline float dist_np(float4 a, float4 b) {
#pragma clang fp contract(off)
  float dx = a.x - b.x, dy = a.y - b.y, dz = a.z - b.z;
  float s = ((dx * dx + dy * dy) + dz * dz) + 1e-6f;
  return sqrtf(s);
}

static __device__ inline unsigned long long umin64(unsigned long long a, unsigned long long b) {
  return a < b ? a : b;
}
static __device__ inline unsigned long long umax64(unsigned long long a, unsigned long long b) {
  return a > b ? a : b;
}

static __device__ inline void rbf16(float d, _Float16* dst) {
  v8h h0, h1;
#pragma unroll
  for (int m = 0; m < 16; ++m) {
    float mu = 2.0f + (20.0f / 15.0f) * (float)m;  // folded at compile time
    float a = (d - mu) * 0.8f;
    float v = __expf(-a * a);
    if (m < 8) h0[m] = (_Float16)v;
    else h1[m - 8] = (_Float16)v;
  }
  *(v8h*)dst = h0;
  *(v8h*)(dst + 8) = h1;
}

static __device__ inline float pdist(const float* qa, const float* nb, int pp) {
  int ia = c_PA[pp] * 3, ib = c_PB[pp] * 3;
  float dx = qa[ia] - nb[ib];
  float dy = qa[ia + 1] - nb[ib + 1];
  float dz = qa[ia + 2] - nb[ib + 2];
  return sqrtf(dx * dx + dy * dy + dz * dz + 1e-6f);
}

// ---------------- prep: atoms (16f rows), compact Ca float4, W_edge -> f16 T ----------------
__global__ __launch_bounds__(256) void prep_kernel(const float* __restrict__ X,
                                                   const float* __restrict__ W_edge,
                                                   float4* __restrict__ atomsP,
                                                   float4* __restrict__ CaP,
                                                   _Float16* __restrict__ Wt) {
  int idx = blockIdx.x * 256 + threadIdx.x;
  if (idx < BB * LL) {
    const float* xp = X + (size_t)idx * 12;
    float Nx = xp[0], Ny = xp[1], Nz = xp[2];
    float Cax = xp[3], Cay = xp[4], Caz = xp[5];
    float Cx = xp[6], Cy = xp[7], Cz = xp[8];
    float Ox = xp[9], Oy = xp[10], Oz = xp[11];
    float bx = Cax - Nx, by = Cay - Ny, bz = Caz - Nz;
    float cx = Cx - Cax, cy = Cy - Cay, cz = Cz - Caz;
    float ax = by * cz - bz * cy;
    float ay = bz * cx - bx * cz;
    float az = bx * cy - by * cx;
    float Cbx = -0.58273431f * ax + 0.56802827f * bx - 0.54067466f * cx + Cax;
    float Cby = -0.58273431f * ay + 0.56802827f * by - 0.54067466f * cy + Cay;
    float Cbz = -0.58273431f * az + 0.56802827f * bz - 0.54067466f * cz + Caz;
    // layout: [N(3) Ca(3) C(3) O(3) Cb(3) pad] as 4x float4
    atomsP[(size_t)idx * 4 + 0] = make_float4(Nx, Ny, Nz, Cax);
    atomsP[(size_t)idx * 4 + 1] = make_float4(Cay, Caz, Cx, Cy);
    atomsP[(size_t)idx * 4 + 2] = make_float4(Cz, Ox, Oy, Oz);
    atomsP[(size_t)idx * 4 + 3] = make_float4(Cbx, Cby, Cbz, 0.f);
    CaP[idx] = make_float4(Cax, Cay, Caz, 0.f);
  } else {
    int t = idx - BB * LL;
    if (t < NOUT * NF) {
      int n = t / NF;
      int k = t - n * NF;
      Wt[t] = (_Float16)W_edge[(size_t)k * NOUT + n];  // Wt[n][k] = W_edge[k][n]
    }
  }
}

// ---------------- top-32 via histogram radix-select + exact bitonic sort ----------------
__global__ __launch_bounds__(256) void topk_kernel(const float4* __restrict__ CaP,
                                                   float* __restrict__ outIdx) {
  __shared__ int hist[NBINS];
  __shared__ unsigned long long cand[NCAND];
  __shared__ int cnt;
  __shared__ int cb_s;
  __shared__ int wtot[4];
  int bid = blockIdx.x;
  int b = bid >> 11;
  int i = bid & (LL - 1);
  int tid = threadIdx.x;
  int lane = tid & 63, wid = tid >> 6;

  for (int t = tid; t < NBINS; t += 256) hist[t] = 0;
  if (tid < NCAND) cand[tid] = ~0ull;
  if (tid == 0) cnt = 0;

  const float4* Cb_ = CaP + (size_t)b * LL;
  float4 ci = Cb_[i];
  unsigned long long key[8];
#pragma unroll
  for (int t = 0; t < 8; ++t) {
    int j = tid + (t << 8);
    float d = dist_np(ci, Cb_[j]);
    key[t] = ((unsigned long long)__float_as_uint(d) << 32) | (unsigned)j;
  }
  __syncthreads();  // hist zeroed
#pragma unroll
  for (int t = 0; t < 8; ++t) {
    atomicAdd(&hist[(int)(key[t] >> 51)], 1);
  }
  __syncthreads();

  // block scan over 256 thread-partials (16 bins each); find crossing bin
  int base_bin = tid * (NBINS / 256);
  int psum = 0;
#pragma unroll
  for (int t = 0; t < NBINS / 256; ++t) psum += hist[base_bin + t];
  int incl = psum;
#pragma unroll
  for (int off = 1; off < 64; off <<= 1) {
    int o = __shfl_up(incl, off);
    if (lane >= off) incl += o;
  }
  if (lane == 63) wtot[wid] = incl;
  __syncthreads();
  int wbase = 0;
  for (int w = 0; w < wid; ++w) wbase += wtot[w];
  int base = wbase + incl - psum;
  if (base < TOPK && base + psum >= TOPK) {
    int run = base;
    for (int t = 0; t < NBINS / 256; ++t) {
      int h = hist[base_bin + t];
      if (run < TOPK && run + h >= TOPK) { cb_s = base_bin + t; break; }
      run += h;
    }
  }
  __syncthreads();

  int cb = cb_s;
#pragma unroll
  for (int t = 0; t < 8; ++t) {
    if ((int)(key[t] >> 51) <= cb) {
      int slot = atomicAdd(&cnt, 1);
      if (slot < NCAND) cand[slot] = key[t];
    }
  }
  __syncthreads();

  if (wid == 0) {  // bitonic sort 128 candidates, 2/lane
    unsigned long long x = cand[lane];
    unsigned long long y = cand[lane + 64];
#pragma unroll
    for (int k = 2; k <= 128; k <<= 1) {
#pragma unroll
      for (int j = 64; j >= 1; j >>= 1) {
        if (j >= k) continue;
        if (j == 64) {
          unsigned long long mn = umin64(x, y), mx = umax64(x, y);
          x = mn; y = mx;
        } else {
          unsigned long long px = __shfl_xor(x, j);
          bool upx = ((lane & k) == 0);
          bool lowx = ((lane & j) == 0);
          x = (lowx == upx) ? umin64(x, px) : umax64(x, px);
          unsigned long long py = __shfl_xor(y, j);
          bool upy = (((lane + 64) & k) == 0);
          y = (lowx == upy) ? umin64(y, py) : umax64(y, py);
        }
      }
    }
    if (lane < TOPK) {
      int j = (int)(x & 0xffffffffull);
      outIdx[bid * TOPK + lane] = (float)j;  // harness reads flat f32; edge reads it back
    }
  }
}

// ---------------- 4 residues/block: features -> f16 MFMA GEMM (K-chunked) -> LayerNorm ----------------
__global__ __launch_bounds__(512, 4) void edge_kernel(
    const float4* __restrict__ atomsP, const float4* __restrict__ CaP,
    const _Float16* __restrict__ Wt, const float* __restrict__ outIdxF,
    const int* __restrict__ ridx, const int* __restrict__ chain,
    const float* __restrict__ W_pos, const float* __restrict__ b_pos,
    const float* __restrict__ gamma, const float* __restrict__ beta,
    float* __restrict__ outE) {
  __shared__ __align__(16) _Float16 Fb[128][FBS];  // 59392 B
  __shared__ float na_f[128][17];                  // neighbor atoms, padded stride
  __shared__ float qa_f[4][16];                    // query atoms per residue
  __shared__ float dnbr_s[128];
  __shared__ int dpos_s[128];
  __shared__ int nidx_s[128];
  __shared__ float partS[128][5];
  __shared__ float partQ[128][5];
  __shared__ float2 mr[128];

  int bid = blockIdx.x;          // group of 4 residues
  int b = bid >> 9;
  int tid = threadIdx.x;
  int g0 = bid * 4;              // first global residue (b*LL + i0 == bid*4)

  if (tid < 128) {
    int r = tid >> 5;
    int j = (int)outIdxF[(size_t)bid * 128 + tid];
    nidx_s[tid] = j;
    dnbr_s[tid] = dist_np(CaP[g0 + r], CaP[(size_t)b * LL + j]);
    int ri = ridx[g0 + r], rj = ridx[b * LL + j];
    int off = ri - rj + 32;
    off = off < 0 ? 0 : (off > 64 ? 64 : off);
    dpos_s[tid] = (chain[g0 + r] == chain[b * LL + j]) ? off : 65;
  } else if (tid < 144) {
    int q16 = tid - 128;
    int r = q16 >> 2, q = q16 & 3;
    float4 v = atomsP[(size_t)(g0 + r) * 4 + q];
    qa_f[r][q * 4 + 0] = v.x; qa_f[r][q * 4 + 1] = v.y;
    qa_f[r][q * 4 + 2] = v.z; qa_f[r][q * 4 + 3] = v.w;
  }
  __syncthreads();

  int e = tid >> 2, g = tid & 3;
  int rr = e >> 5;
  {  // neighbor atoms: one coalesced float4/thread; readers of na_f[e] are the same quad
    float4 v = atomsP[((size_t)b * LL + nidx_s[e]) * 4 + g];
    na_f[e][g * 4 + 0] = v.x; na_f[e][g * 4 + 1] = v.y;
    na_f[e][g * 4 + 2] = v.z; na_f[e][g * 4 + 3] = v.w;
  }

  // ---- fill chunk0: cols 0..223 = pos(16) + R0(16) + pairs 0..11 ----
  {
    int dp = dpos_s[e];
    v4h hp;
#pragma unroll
    for (int t = 0; t < 4; ++t)
      hp[t] = (_Float16)(W_pos[dp * 16 + g * 4 + t] + b_pos[g * 4 + t]);
    *(v4h*)&Fb[e][g * 4] = hp;
  }
  for (int s = g; s < 13; s += 4) {
    float d;
    int col;
    if (s == 0) { d = dnbr_s[e]; col = 16; }
    else { int pp = s - 1; col = 32 + pp * 16; d = pdist(qa_f[rr], na_f[e], pp); }
    rbf16(d, &Fb[e][col]);
  }
  __syncthreads();

  // ---- GEMM: waves (mt: 64 rows) x (nh: 32 cols); acc carried across chunks ----
  int lane = tid & 63, wv = tid >> 6;
  int mt = wv & 1, nh = wv >> 1;
  int lm = lane & 15, lq = lane >> 4;
  const _Float16* bp0 = Wt + (size_t)(nh * 32 + lm) * NF + lq * 8;
  const _Float16* bp1 = bp0 + 16 * NF;
  v4f acc[4][2];
#pragma unroll
  for (int t = 0; t < 4; ++t) { acc[t][0] = (v4f){0,0,0,0}; acc[t][1] = (v4f){0,0,0,0}; }

#pragma unroll
  for (int kk = 0; kk < 7; ++kk) {  // chunk0: K=224
    int k = kk * 32;
    v8h B0 = *(const v8h*)(bp0 + k);
    v8h B1 = *(const v8h*)(bp1 + k);
#pragma unroll
    for (int t = 0; t < 4; ++t) {
      v8h A = *(const v8h*)&Fb[mt * 64 + t * 16 + lm][lq * 8 + k];
      acc[t][0] = __builtin_amdgcn_mfma_f32_16x16x32_f16(A, B0, acc[t][0], 0, 0, 0);
      acc[t][1] = __builtin_amdgcn_mfma_f32_16x16x32_f16(A, B1, acc[t][1], 0, 0, 0);
    }
  }
  __syncthreads();  // GEMM chunk0 done before Fb refill

  // ---- fill chunk1: cols 224..415 = pairs 12..23 (local col = s*16) ----
  for (int s = g; s < 12; s += 4) {
    int pp = 12 + s;
    float d = pdist(qa_f[rr], na_f[e], pp);
    rbf16(d, &Fb[e][s * 16]);
  }
  __syncthreads();

#pragma unroll
  for (int kk = 0; kk < 6; ++kk) {  // chunk1: K=192, global k offset 224
    int k = kk * 32;
    v8h B0 = *(const v8h*)(bp0 + 224 + k);
    v8h B1 = *(const v8h*)(bp1 + 224 + k);
#pragma unroll
    for (int t = 0; t < 4; ++t) {
      v8h A = *(const v8h*)&Fb[mt * 64 + t * 16 + lm][lq * 8 + k];
      acc[t][0] = __builtin_amdgcn_mfma_f32_16x16x32_f16(A, B0, acc[t][0], 0, 0, 0);
      acc[t][1] = __builtin_amdgcn_mfma_f32_16x16x32_f16(A, B1, acc[t][1], 0, 0, 0);
    }
  }

  // ---- LayerNorm: per-row 32-col partials -> LDS -> combine -> store ----
#pragma unroll
  for (int t = 0; t < 4; ++t) {
#pragma unroll
    for (int r = 0; r < 4; ++r) {
      float s = acc[t][0][r] + acc[t][1][r];
      float q = acc[t][0][r] * acc[t][0][r] + acc[t][1][r] * acc[t][1][r];
#pragma unroll
      for (int off = 1; off <= 8; off <<= 1) {
        s += __shfl_xor(s, off);
        q += __shfl_xor(q, off);
      }
      if (lm == 0) {
        int row = mt * 64 + t * 16 + lq * 4 + r;
        partS[row][nh] = s;
        partQ[row][nh] = q;
      }
    }
  }
  __syncthreads();
  if (tid < 128) {
    float S = (partS[tid][0] + partS[tid][1]) + (partS[tid][2] + partS[tid][3]);
    float Q = (partQ[tid][0] + partQ[tid][1]) + (partQ[tid][2] + partQ[tid][3]);
    float mean = S * (1.0f / 128.0f);
    float var = Q * (1.0f / 128.0f) - mean * mean;
    mr[tid] = make_float2(mean, 1.0f / sqrtf(var + 1e-5f));
  }
  __syncthreads();
  float gm0 = gamma[nh * 32 + lm], gm1 = gamma[nh * 32 + 16 + lm];
  float bt0 = beta[nh * 32 + lm], bt1 = beta[nh * 32 + 16 + lm];
  float* op = outE + (size_t)bid * 128 * NOUT + nh * 32 + lm;
#pragma unroll
  for (int t = 0; t < 4; ++t) {
#pragma unroll
    for (int r = 0; r < 4; ++r) {
      int row = mt * 64 + t * 16 + lq * 4 + r;
      float2 m = mr[row];
      float* p = op + (size_t)row * NOUT;
      p[0]  = (acc[t][0][r] - m.x) * m.y * gm0 + bt0;
      p[16] = (acc[t][1][r] - m.x) * m.y * gm1 + bt1;
    }
  }
}

extern "C" void kernel_launch(void* const* d_in, const int* in_sizes, int n_in,
                              void* d_out, int out_size, void* d_ws, size_t ws_size,
                              hipStream_t stream) {
  const float* X = (const float*)d_in[0];
  const int* ridx = (const int*)d_in[2];
  const int* chain = (const int*)d_in[3];
  const float* W_pos = (const float*)d_in[4];
  const float* b_pos = (const float*)d_in[5];
  const float* W_edge = (const float*)d_in[6];
  const float* gamma = (const float*)d_in[7];
  const float* beta = (const float*)d_in[8];

  float* outE = (float*)d_out;
  float* outIdx = outE + (size_t)BB * LL * TOPK * NOUT;

  char* ws = (char*)d_ws;
  float4* atomsP = (float4*)(ws + OFF_ATOMS);
  float4* CaP = (float4*)(ws + OFF_CA);
  _Float16* Wt = (_Float16*)(ws + OFF_WT);

  prep_kernel<<<240, 256, 0, stream>>>(X, W_edge, atomsP, CaP, Wt);
  topk_kernel<<<BB * LL, 256, 0, stream>>>(CaP, outIdx);
  edge_kernel<<<BB * LL / 4, 512, 0, stream>>>(atomsP, CaP, Wt, outIdx, ridx, chain,
                                               W_pos, b_pos, gamma, beta, outE);
}